// Round 13
// baseline (225.765 us; speedup 1.0000x reference)
//
#include <hip/hip_runtime.h>
#include <hip/hip_bf16.h>

#define N_NODES 100000
#define N_EDGES 1600000
#define HID 128
#define N_GRAPHS 256

#define BSHIFT 9
#define BSIZE 512
#define NBUCK ((N_NODES + BSIZE - 1) / BSIZE)   // 196
#define BCAP 12288
#define EPB 8192
#define NBLK_A ((N_EDGES + EPB - 1) / EPB)      // 196
#define NCLS 16
#define ZOFF ((uint)N_NODES << 8)                // byte offset of the zero row

typedef unsigned int uint;
typedef unsigned short ushort;
typedef short short8 __attribute__((ext_vector_type(8)));
typedef float f32x4 __attribute__((ext_vector_type(4)));

__device__ __forceinline__ ushort f2bf_hw(float f) {
    union { __hip_bfloat16 b; ushort u; } cv;
    cv.b = __float2bfloat16(f);
    return cv.u;
}
__device__ __forceinline__ uint4 pack8(const float* r) {
    uint4 o;
    o.x = (uint)f2bf_hw(r[0]) | ((uint)f2bf_hw(r[1]) << 16);
    o.y = (uint)f2bf_hw(r[2]) | ((uint)f2bf_hw(r[3]) << 16);
    o.z = (uint)f2bf_hw(r[4]) | ((uint)f2bf_hw(r[5]) << 16);
    o.w = (uint)f2bf_hw(r[6]) | ((uint)f2bf_hw(r[7]) << 16);
    return o;
}
// accumulate 8 bf16 (packed uint4) into 4 float2 (paired for v_pk_add_f32)
__device__ __forceinline__ void accp(uint4 v, float2* a) {
    a[0].x += __uint_as_float(v.x << 16);
    a[0].y += __uint_as_float(v.x & 0xFFFF0000u);
    a[1].x += __uint_as_float(v.y << 16);
    a[1].y += __uint_as_float(v.y & 0xFFFF0000u);
    a[2].x += __uint_as_float(v.z << 16);
    a[2].y += __uint_as_float(v.z & 0xFFFF0000u);
    a[3].x += __uint_as_float(v.w << 16);
    a[3].y += __uint_as_float(v.w & 0xFFFF0000u);
}

union Frag16 {
    uint4 u;
    short8 s;
    ushort h[8];
};

__device__ __forceinline__ void pack_w(const float* W, uint4* WB, int tt) {
    int lane = tt & 63;
    int nt = (tt >> 6) & 7;
    int kt = tt >> 9;
    int kbase = kt * 32 + (lane >> 4) * 8;
    int col = nt * 16 + (lane & 15);
    float r[8];
#pragma unroll
    for (int j = 0; j < 8; j++) r[j] = W[(size_t)(kbase + j) * 128 + col];
    WB[tt] = pack8(r);
}

// ---------------- bucketed edge scatter (+ W-frag pack in spare blocks) ----------------
__global__ __launch_bounds__(256) void bucket_scatter_kernel(const int* __restrict__ src,
                                                             const int* __restrict__ dst,
                                                             int* __restrict__ bfill,
                                                             uint* __restrict__ bucketed,
                                                             const float* __restrict__ W1,
                                                             const float* __restrict__ W2,
                                                             uint4* __restrict__ WB1,
                                                             uint4* __restrict__ WB2) {
    if (blockIdx.x >= NBLK_A) {
        // W fragment pre-pack: 16 blocks x 256 threads = 4096 frags
        int t = (blockIdx.x - NBLK_A) * 256 + threadIdx.x;
        if (t < 2048) pack_w(W1, WB1, t);
        else          pack_w(W2, WB2, t & 2047);
        return;
    }
    __shared__ int h[NBUCK];
    __shared__ int rb[NBUCK];
    for (int t = threadIdx.x; t < NBUCK; t += 256) h[t] = 0;
    __syncthreads();
    int base = blockIdx.x * EPB;
#pragma unroll 4
    for (int it = 0; it < EPB / 256; ++it) {
        int e = base + it * 256 + threadIdx.x;
        if (e < N_EDGES) atomicAdd(&h[dst[e] >> BSHIFT], 1);
    }
    __syncthreads();
    for (int t = threadIdx.x; t < NBUCK; t += 256) {
        rb[t] = (h[t] ? atomicAdd(&bfill[t], h[t]) : 0) + t * BCAP;
        h[t] = 0;
    }
    __syncthreads();
#pragma unroll 4
    for (int it = 0; it < EPB / 256; ++it) {
        int e = base + it * 256 + threadIdx.x;
        if (e < N_EDGES) {
            int d = dst[e];
            int b = d >> BSHIFT;
            int pos = rb[b] + atomicAdd(&h[b], 1);
            bucketed[pos] = (uint)src[e] | ((uint)(d & (BSIZE - 1)) << 17);
        }
    }
}

// one block per bucket: count/scan/scatter. Segments padded to multiple of 4 (ZOFF fill);
// degi holds PADDED count; builds degree-class histogram; LAST block computes clsbase.
__global__ __launch_bounds__(256) void bucket_csr_kernel(const uint* __restrict__ bucketed,
                                                         const int* __restrict__ bfill,
                                                         int* __restrict__ degi,
                                                         int* __restrict__ rowptr,
                                                         float* __restrict__ dis,
                                                         uint* __restrict__ csrb,
                                                         int* __restrict__ clshist,
                                                         int* __restrict__ donecnt,
                                                         int* __restrict__ clsbase) {
    int b = blockIdx.x;
    int beg = b * BCAP;
    int ne = bfill[b];
    __shared__ int cnt[BSIZE];
    __shared__ int fl[BSIZE];
    __shared__ int ex[BSIZE];
    __shared__ int ps[256];
    __shared__ int ch[NCLS];
    int t = threadIdx.x;
    cnt[t] = 0; cnt[t + 256] = 0;
    fl[t] = 0;  fl[t + 256] = 0;
    if (t < NCLS) ch[t] = 0;
    __syncthreads();
    for (int i = t; i < ne; i += 256) atomicAdd(&cnt[bucketed[beg + i] >> 17], 1);
    __syncthreads();
    int v0 = cnt[2 * t], v1 = cnt[2 * t + 1];
    int p0 = (v0 + 3) & ~3;
    int p1 = (v1 + 3) & ~3;
    int s = p0 + p1;
    ps[t] = s;
    __syncthreads();
    for (int off = 1; off < 256; off <<= 1) {
        int a = (t >= off) ? ps[t - off] : 0;
        __syncthreads();
        ps[t] += a;
        __syncthreads();
    }
    int e0 = ps[t] - s;
    ex[2 * t] = e0;
    ex[2 * t + 1] = e0 + p0;
    int g = b * BSIZE + 2 * t;
    if (g < N_NODES) {
        degi[g] = p0; rowptr[g] = beg + e0;
        dis[g] = rsqrtf(1.0f + (float)v0);
        atomicAdd(&ch[min(p0 >> 2, NCLS - 1)], 1);
    }
    if (g + 1 < N_NODES) {
        degi[g + 1] = p1; rowptr[g + 1] = beg + e0 + p0;
        dis[g + 1] = rsqrtf(1.0f + (float)v1);
        atomicAdd(&ch[min(p1 >> 2, NCLS - 1)], 1);
    }
    __syncthreads();
    if (t < NCLS && ch[t]) atomicAdd(&clshist[t], ch[t]);
    for (int i = t; i < ne; i += 256) {
        uint u = bucketed[beg + i];
        int dl = u >> 17;
        int p = ex[dl] + atomicAdd(&fl[dl], 1);
        csrb[beg + p] = (u & 0x1FFFFu) << 8;   // byte offset: src * 256
    }
    __syncthreads();
    for (int p = v0; p < p0; ++p) csrb[beg + ex[2 * t] + p] = ZOFF;
    for (int p = v1; p < p1; ++p) csrb[beg + ex[2 * t + 1] + p] = ZOFF;
    // last finished block computes the 16-entry class-base prefix
    __syncthreads();
    if (t == 0) {
        __threadfence();
        int d = atomicAdd(donecnt, 1);
        if (d == NBUCK - 1) {
            int run = 0;
            for (int c = 0; c < NCLS; ++c) {
                int v = atomicAdd(&clshist[c], 0);  // device-scope atomic read
                clsbase[c] = run; run += v;
            }
        }
    }
}

// ---------------- perm (degree-class permutation) + xprep (X' = bf16(dis*x)) ----------------
__global__ __launch_bounds__(256) void permxprep_kernel(const int* __restrict__ degi,
                                                        const int* __restrict__ clsbase,
                                                        int* __restrict__ clsfill,
                                                        int* __restrict__ perm,
                                                        const float* __restrict__ x,
                                                        const float* __restrict__ dis,
                                                        uint4* __restrict__ Xp) {
    __shared__ int h[NCLS];
    __shared__ int rb[NCLS];
    int t = threadIdx.x;
    if (t < NCLS) h[t] = 0;
    __syncthreads();
    int n = blockIdx.x * 256 + t;
    int cls = 0, myloc = 0;
    if (n < N_NODES) {
        cls = min(degi[n] >> 2, NCLS - 1);
        myloc = atomicAdd(&h[cls], 1);
    }
    __syncthreads();
    if (t < NCLS) rb[t] = h[t] ? (clsbase[t] + atomicAdd(&clsfill[t], h[t])) : 0;
    __syncthreads();
    if (n < N_NODES) perm[rb[cls] + myloc] = n;

    // xprep: this block converts 256 nodes' rows (4096 uint4, 16 per thread)
    int base = blockIdx.x * 4096;
#pragma unroll
    for (int i = 0; i < 16; ++i) {
        int idx = base + i * 256 + t;
        if (idx < N_NODES * 16) {
            int nn = idx >> 4, c16 = idx & 15;
            const float* xr = x + (size_t)nn * 128 + c16 * 8;
            float d = dis[nn];
            float4 lo = *(const float4*)xr;
            float4 hi = *(const float4*)(xr + 4);
            float r[8] = {d * lo.x, d * lo.y, d * lo.z, d * lo.w,
                          d * hi.x, d * hi.y, d * hi.z, d * hi.w};
            Xp[idx] = pack8(r);
        }
    }
}

// ---------------- fused aggregate + GEMM (+ optional pool dot) ----------------
// Block = 16 nodes (class-uniform via perm). Group (16 lanes) owns one node's gather.
// u = dis[n]*(sum_nbr T[s] + T[n]) -> A-tile (bf16, LDS) -> M=16 MFMA @ W -> epilogue.
// POOL=0: H[n] = bf16(dis[n]*relu(u@W + b));  POOL=1: ndot[n] = relu(u@W + b) . Wfc
template <int POOL>
__global__ __launch_bounds__(256, 8) void fused_agg_kernel(
    const ushort* __restrict__ T, const uint* __restrict__ csrb,
    const int* __restrict__ rowptr, const int* __restrict__ degi,
    const float* __restrict__ dis, const float* __restrict__ bias,
    const int* __restrict__ perm, const uint4* __restrict__ WB,
    ushort* __restrict__ H, const float* __restrict__ Wfc,
    float* __restrict__ ndot) {
    __shared__ ushort At[16][136];      // 272B row stride (bank-spread)
    __shared__ float disrow[16];
    __shared__ int nid[16];
    __shared__ float pdot[16][4];

    int wave = threadIdx.x >> 6;
    int lane = threadIdx.x & 63;
    int group = lane >> 4;
    int sub = lane & 15;
    uint sub16 = (uint)sub * 16u;
    int r = wave * 4 + group;                       // tile row 0..15
    int node = perm[blockIdx.x * 16 + r];           // grid exact: N_NODES%16==0
    int start = rowptr[node];
    int iters = degi[node] >> 2;
    const char* Tb = (const char*)T;

    float2 acc[4];
#pragma unroll
    for (int i = 0; i < 4; i++) acc[i] = make_float2(0.f, 0.f);

    int jb = start;
    for (int it = 0; it < iters; ++it, jb += 4) {
        uint o0 = csrb[jb];
        uint o1 = csrb[jb + 1];
        uint o2 = csrb[jb + 2];
        uint o3 = csrb[jb + 3];
        uint4 v0 = *(const uint4*)(Tb + (o0 + sub16));
        uint4 v1 = *(const uint4*)(Tb + (o1 + sub16));
        uint4 v2 = *(const uint4*)(Tb + (o2 + sub16));
        uint4 v3 = *(const uint4*)(Tb + (o3 + sub16));
        accp(v0, acc); accp(v1, acc); accp(v2, acc); accp(v3, acc);
    }
    // self term, then scale by dis[node] -> u-row (bf16) into A tile
    {
        uint4 sv = *(const uint4*)(Tb + (((uint)node << 8) + sub16));
        accp(sv, acc);
        float di = dis[node];
        float rr[8] = {di * acc[0].x, di * acc[0].y, di * acc[1].x, di * acc[1].y,
                       di * acc[2].x, di * acc[2].y, di * acc[3].x, di * acc[3].y};
        *(uint4*)&At[r][sub * 8] = pack8(rr);
        if (sub == 0) { disrow[r] = di; nid[r] = node; }
    }
    __syncthreads();

    // MFMA: wave handles nt = wave*2, wave*2+1 over the 16x128 tile
    Frag16 a[4];
    int arow = lane & 15;
    int achunk = lane >> 4;
#pragma unroll
    for (int kt = 0; kt < 4; ++kt)
        a[kt].u = *(const uint4*)&At[arow][kt * 32 + achunk * 8];

    f32x4 c0 = (f32x4){0.f, 0.f, 0.f, 0.f};
    f32x4 c1 = (f32x4){0.f, 0.f, 0.f, 0.f};
    int nt0 = wave * 2, nt1 = wave * 2 + 1;
#pragma unroll
    for (int kt = 0; kt < 4; ++kt) {
        Frag16 b0, b1;
        b0.u = WB[(kt * 8 + nt0) * 64 + lane];
        b1.u = WB[(kt * 8 + nt1) * 64 + lane];
        c0 = __builtin_amdgcn_mfma_f32_16x16x32_bf16(a[kt].s, b0.s, c0, 0, 0, 0);
        c1 = __builtin_amdgcn_mfma_f32_16x16x32_bf16(a[kt].s, b1.s, c1, 0, 0, 0);
    }

    // C layout: col = lane&15, row = (lane>>4)*4 + reg
    int col0 = nt0 * 16 + sub, col1 = nt1 * 16 + sub;
    float b0s = bias[col0], b1s = bias[col1];
    int rq = (lane >> 4) * 4;

    if (POOL == 0) {
        __syncthreads();   // all A-reads done; reuse At as output stage
#pragma unroll
        for (int reg = 0; reg < 4; ++reg) {
            float sc = disrow[rq + reg];
            At[rq + reg][col0] = f2bf_hw(fmaxf(c0[reg] + b0s, 0.f) * sc);
            At[rq + reg][col1] = f2bf_hw(fmaxf(c1[reg] + b1s, 0.f) * sc);
        }
        __syncthreads();
        int row = threadIdx.x >> 4, c16 = threadIdx.x & 15;
        uint4 v = *(const uint4*)&At[row][c16 * 8];
        *(uint4*)((char*)H + (((size_t)(uint)nid[row]) << 8) + c16 * 16) = v;
    } else {
        float wf0 = Wfc[col0], wf1 = Wfc[col1];
        float p[4];
#pragma unroll
        for (int reg = 0; reg < 4; ++reg)
            p[reg] = fmaxf(c0[reg] + b0s, 0.f) * wf0 + fmaxf(c1[reg] + b1s, 0.f) * wf1;
#pragma unroll
        for (int reg = 0; reg < 4; ++reg) {
            p[reg] += __shfl_xor(p[reg], 1);
            p[reg] += __shfl_xor(p[reg], 2);
            p[reg] += __shfl_xor(p[reg], 4);
            p[reg] += __shfl_xor(p[reg], 8);
        }
        if (sub == 0) {
#pragma unroll
            for (int reg = 0; reg < 4; ++reg) pdot[rq + reg][wave] = p[reg];
        }
        __syncthreads();
        if (threadIdx.x < 16) {
            int row = threadIdx.x;
            ndot[nid[row]] = pdot[row][0] + pdot[row][1] + pdot[row][2] + pdot[row][3];
        }
    }
}

// ---------------- pool+fc: one wave per graph over sorted batch ----------------
__global__ __launch_bounds__(64) void pool_fc_kernel(const float* __restrict__ ndot,
                                                     const int* __restrict__ batch,
                                                     const float* __restrict__ bfc,
                                                     float* __restrict__ out) {
    int g = blockIdx.x;
    int lane = threadIdx.x;
    auto lb = [&](int key) {
        int lo = 0, hi = N_NODES;
        while (lo < hi) {
            int mid = (lo + hi) >> 1;
            if (batch[mid] < key) lo = mid + 1; else hi = mid;
        }
        return lo;
    };
    int a = lb(g), b = lb(g + 1);
    float s = 0.f;
    for (int i = a + lane; i < b; i += 64) s += ndot[i];
#pragma unroll
    for (int off = 32; off > 0; off >>= 1) s += __shfl_down(s, off);
    if (lane == 0) out[g] = s / fmaxf((float)(b - a), 1.0f) + bfc[0];
}

// ---------------- launcher ----------------
extern "C" void kernel_launch(void* const* d_in, const int* in_sizes, int n_in,
                              void* d_out, int out_size, void* d_ws, size_t ws_size,
                              hipStream_t stream) {
    const float* x    = (const float*)d_in[0];
    const int*   eidx = (const int*)d_in[1];
    const int*   batch= (const int*)d_in[2];
    const float* W1   = (const float*)d_in[3];
    const float* b1   = (const float*)d_in[4];
    const float* W2   = (const float*)d_in[5];
    const float* b2   = (const float*)d_in[6];
    const float* Wfc  = (const float*)d_in[7];
    const float* bfc  = (const float*)d_in[8];
    float* out = (float*)d_out;

    const int* src = eidx;
    const int* dst = eidx + N_EDGES;

    size_t off = 0;
    char* base = (char*)d_ws;
    auto alloc = [&](size_t bytes) -> void* {
        void* p = base + off;
        off += (bytes + 255) & ~(size_t)255;
        return p;
    };
    // zero region (one memset): donecnt, clshist, clsfill, bfill
    int*    donecnt = (int*)alloc(4);
    int*    clshist = (int*)alloc(NCLS * 4);
    int*    clsfill = (int*)alloc(NCLS * 4);
    int*    bfill   = (int*)alloc(NBUCK * 4);
    size_t zero_bytes = off;
    int*    clsbase = (int*)alloc(NCLS * 4);
    ushort* A       = (ushort*)alloc((size_t)(N_NODES + 1) * HID * 2);
    ushort* B       = (ushort*)alloc((size_t)(N_NODES + 1) * HID * 2);
    int*    degi    = (int*)alloc(N_NODES * 4);
    int*    rowptr  = (int*)alloc(N_NODES * 4);
    float*  dis     = (float*)alloc(N_NODES * 4);
    float*  ndot    = (float*)alloc(N_NODES * 4);
    int*    perm    = (int*)alloc(N_NODES * 4);
    uint*   csrb    = (uint*)alloc((size_t)NBUCK * BCAP * 4);
    uint*   bucketed= (uint*)alloc((size_t)NBUCK * BCAP * 4);
    uint4*  WB1     = (uint4*)alloc(2048 * 16);
    uint4*  WB2     = (uint4*)alloc(2048 * 16);

    // zero: counters + the dummy zero rows of A and B (DMA memsets, capture-safe)
    hipMemsetAsync(base, 0, zero_bytes, stream);
    hipMemsetAsync(A + (size_t)N_NODES * HID, 0, HID * 2, stream);
    hipMemsetAsync(B + (size_t)N_NODES * HID, 0, HID * 2, stream);

    // scatter (+W pack in spare blocks) -> csr (+clsbase in last block)
    bucket_scatter_kernel<<<NBLK_A + 16, 256, 0, stream>>>(src, dst, bfill, bucketed,
                                                           W1, W2, WB1, WB2);
    bucket_csr_kernel<<<NBUCK, 256, 0, stream>>>(bucketed, bfill, degi, rowptr, dis,
                                                 csrb, clshist, donecnt, clsbase);
    // perm + xprep fused
    permxprep_kernel<<<(N_NODES + 255) / 256, 256, 0, stream>>>(degi, clsbase, clsfill,
                                                                perm, x, dis, (uint4*)A);

    int fgrid = N_NODES / 16;   // 6250 exact

    // layer 1: gather X' -> @W1 -> relu -> *dis -> B (h1')
    fused_agg_kernel<0><<<fgrid, 256, 0, stream>>>(A, csrb, rowptr, degi, dis, b1,
                                                   perm, WB1, B, Wfc, ndot);
    // layer 2: gather h1' -> @W2 -> relu -> dot Wfc -> ndot
    fused_agg_kernel<1><<<fgrid, 256, 0, stream>>>(B, csrb, rowptr, degi, dis, b2,
                                                   perm, WB2, B, Wfc, ndot);

    // pool + fc
    pool_fc_kernel<<<N_GRAPHS, 64, 0, stream>>>(ndot, batch, bfc, out);
}

// Round 14
// 211.591 us; speedup vs baseline: 1.0670x; 1.0670x over previous
//
#include <hip/hip_runtime.h>
#include <hip/hip_bf16.h>

#define N_NODES 100000
#define N_EDGES 1600000
#define HID 128
#define N_GRAPHS 256

#define BSHIFT 9
#define BSIZE 512
#define NBUCK ((N_NODES + BSIZE - 1) / BSIZE)   // 196
#define BCAP 12288
#define EPB 8192
#define NBLK_A ((N_EDGES + EPB - 1) / EPB)      // 196
#define NCLS 16
#define ZOFF ((uint)N_NODES << 8)                // byte offset of the zero row

typedef unsigned int uint;
typedef unsigned short ushort;
typedef short short8 __attribute__((ext_vector_type(8)));
typedef float f32x4 __attribute__((ext_vector_type(4)));

__device__ __forceinline__ ushort f2bf_hw(float f) {
    union { __hip_bfloat16 b; ushort u; } cv;
    cv.b = __float2bfloat16(f);
    return cv.u;
}
__device__ __forceinline__ uint4 pack8(const float* r) {
    uint4 o;
    o.x = (uint)f2bf_hw(r[0]) | ((uint)f2bf_hw(r[1]) << 16);
    o.y = (uint)f2bf_hw(r[2]) | ((uint)f2bf_hw(r[3]) << 16);
    o.z = (uint)f2bf_hw(r[4]) | ((uint)f2bf_hw(r[5]) << 16);
    o.w = (uint)f2bf_hw(r[6]) | ((uint)f2bf_hw(r[7]) << 16);
    return o;
}
// accumulate 8 bf16 (packed uint4) into 4 float2 (paired for v_pk_add_f32)
__device__ __forceinline__ void accp(uint4 v, float2* a) {
    a[0].x += __uint_as_float(v.x << 16);
    a[0].y += __uint_as_float(v.x & 0xFFFF0000u);
    a[1].x += __uint_as_float(v.y << 16);
    a[1].y += __uint_as_float(v.y & 0xFFFF0000u);
    a[2].x += __uint_as_float(v.z << 16);
    a[2].y += __uint_as_float(v.z & 0xFFFF0000u);
    a[3].x += __uint_as_float(v.w << 16);
    a[3].y += __uint_as_float(v.w & 0xFFFF0000u);
}

union Frag16 {
    uint4 u;
    short8 s;
    ushort h[8];
};

// ---------------- setup: zero counters + zero rows, and pack W frags ----------------
__global__ void setup_kernel(int* __restrict__ bfill, int* __restrict__ clshist,
                             int* __restrict__ clsfill,
                             uint4* __restrict__ Azr, uint4* __restrict__ Bzr,
                             const float* __restrict__ W1, const float* __restrict__ W2,
                             uint4* __restrict__ WB1, uint4* __restrict__ WB2) {
    if (blockIdx.x == 0) {
        int t = threadIdx.x;
        if (t < NBUCK) bfill[t] = 0;
        if (t < NCLS) { clshist[t] = 0; clsfill[t] = 0; }
        if (t < 16) Azr[t] = (uint4){0, 0, 0, 0};
        else if (t < 32) Bzr[t - 16] = (uint4){0, 0, 0, 0};
        return;
    }
    int t = (blockIdx.x - 1) * 256 + threadIdx.x;   // 0..4095
    const float* W = (t < 2048) ? W1 : W2;
    uint4* WB = (t < 2048) ? WB1 : WB2;
    int tt = t & 2047;
    int lane = tt & 63;
    int nt = (tt >> 6) & 7;
    int kt = tt >> 9;
    int kbase = kt * 32 + (lane >> 4) * 8;
    int col = nt * 16 + (lane & 15);
    float r[8];
#pragma unroll
    for (int j = 0; j < 8; j++) r[j] = W[(size_t)(kbase + j) * 128 + col];
    WB[tt] = pack8(r);
}

// ---------------- bucketed CSR build ----------------
__global__ __launch_bounds__(256) void bucket_scatter_kernel(const int* __restrict__ src,
                                                             const int* __restrict__ dst,
                                                             int* __restrict__ bfill,
                                                             uint* __restrict__ bucketed) {
    __shared__ int h[NBUCK];
    __shared__ int rb[NBUCK];
    for (int t = threadIdx.x; t < NBUCK; t += 256) h[t] = 0;
    __syncthreads();
    int base = blockIdx.x * EPB;
#pragma unroll 4
    for (int it = 0; it < EPB / 256; ++it) {
        int e = base + it * 256 + threadIdx.x;
        if (e < N_EDGES) atomicAdd(&h[dst[e] >> BSHIFT], 1);
    }
    __syncthreads();
    for (int t = threadIdx.x; t < NBUCK; t += 256) {
        rb[t] = (h[t] ? atomicAdd(&bfill[t], h[t]) : 0) + t * BCAP;
        h[t] = 0;
    }
    __syncthreads();
#pragma unroll 4
    for (int it = 0; it < EPB / 256; ++it) {
        int e = base + it * 256 + threadIdx.x;
        if (e < N_EDGES) {
            int d = dst[e];
            int b = d >> BSHIFT;
            int pos = rb[b] + atomicAdd(&h[b], 1);
            bucketed[pos] = (uint)src[e] | ((uint)(d & (BSIZE - 1)) << 17);
        }
    }
}

// one block per bucket: stage bucket in LDS, count/scan/scatter.
// Segments padded to multiple of 4 (ZOFF fill); degi holds PADDED count;
// also builds the degree-class histogram.
__global__ __launch_bounds__(256) void bucket_csr_kernel(const uint* __restrict__ bucketed,
                                                         const int* __restrict__ bfill,
                                                         int* __restrict__ degi,
                                                         int* __restrict__ rowptr,
                                                         float* __restrict__ dis,
                                                         uint* __restrict__ csrb,
                                                         int* __restrict__ clshist) {
    int b = blockIdx.x;
    int beg = b * BCAP;
    int ne = bfill[b];
    __shared__ uint eb[BCAP];          // 48 KB bucket stage (read bucketed ONCE)
    __shared__ int cnt[BSIZE];
    __shared__ int fl[BSIZE];
    __shared__ int ex[BSIZE];
    __shared__ int ps[256];
    __shared__ int ch[NCLS];
    int t = threadIdx.x;
    cnt[t] = 0; cnt[t + 256] = 0;
    fl[t] = 0;  fl[t + 256] = 0;
    if (t < NCLS) ch[t] = 0;
    __syncthreads();
    for (int i = t; i < ne; i += 256) {
        uint u = bucketed[beg + i];
        eb[i] = u;
        atomicAdd(&cnt[u >> 17], 1);
    }
    __syncthreads();
    int v0 = cnt[2 * t], v1 = cnt[2 * t + 1];
    int p0 = (v0 + 3) & ~3;
    int p1 = (v1 + 3) & ~3;
    int s = p0 + p1;
    ps[t] = s;
    __syncthreads();
    for (int off = 1; off < 256; off <<= 1) {
        int a = (t >= off) ? ps[t - off] : 0;
        __syncthreads();
        ps[t] += a;
        __syncthreads();
    }
    int e0 = ps[t] - s;
    ex[2 * t] = e0;
    ex[2 * t + 1] = e0 + p0;
    int g = b * BSIZE + 2 * t;
    if (g < N_NODES) {
        degi[g] = p0; rowptr[g] = beg + e0;
        dis[g] = rsqrtf(1.0f + (float)v0);
        atomicAdd(&ch[min(p0 >> 2, NCLS - 1)], 1);
    }
    if (g + 1 < N_NODES) {
        degi[g + 1] = p1; rowptr[g + 1] = beg + e0 + p0;
        dis[g + 1] = rsqrtf(1.0f + (float)v1);
        atomicAdd(&ch[min(p1 >> 2, NCLS - 1)], 1);
    }
    __syncthreads();
    if (t < NCLS && ch[t]) atomicAdd(&clshist[t], ch[t]);
    for (int i = t; i < ne; i += 256) {
        uint u = eb[i];
        int dl = u >> 17;
        int p = ex[dl] + atomicAdd(&fl[dl], 1);
        csrb[beg + p] = (u & 0x1FFFFu) << 8;   // byte offset: src * 256
    }
    __syncthreads();
    for (int p = v0; p < p0; ++p) csrb[beg + ex[2 * t] + p] = ZOFF;
    for (int p = v1; p < p1; ++p) csrb[beg + ex[2 * t + 1] + p] = ZOFF;
}

// ---------------- class bases (16 values, serial) ----------------
__global__ void clsbase_kernel(const int* __restrict__ clshist, int* __restrict__ clsbase) {
    if (threadIdx.x == 0) {
        int run = 0;
        for (int c = 0; c < NCLS; ++c) { clsbase[c] = run; run += clshist[c]; }
    }
}

// ---------------- degree-class permutation (hierarchical, low-contention) ----------------
__global__ __launch_bounds__(256) void perm_kernel(const int* __restrict__ degi,
                                                   const int* __restrict__ clsbase,
                                                   int* __restrict__ clsfill,
                                                   int* __restrict__ perm) {
    __shared__ int h[NCLS];
    __shared__ int rb[NCLS];
    int t = threadIdx.x;
    if (t < NCLS) h[t] = 0;
    __syncthreads();
    int n = blockIdx.x * 256 + t;
    int cls = 0, myloc = 0;
    if (n < N_NODES) {
        cls = min(degi[n] >> 2, NCLS - 1);
        myloc = atomicAdd(&h[cls], 1);
    }
    __syncthreads();
    if (t < NCLS) rb[t] = h[t] ? (clsbase[t] + atomicAdd(&clsfill[t], h[t])) : 0;
    __syncthreads();
    if (n < N_NODES) perm[rb[cls] + myloc] = n;
}

// ---------------- xprep: X' = bf16(dis[n] * x[n]) ----------------
__global__ __launch_bounds__(256) void xprep_kernel(const float* __restrict__ x,
                                                    const float* __restrict__ dis,
                                                    uint4* __restrict__ Xp) {
    int t = blockIdx.x * 256 + threadIdx.x;      // 1.6M = N_NODES*16
    if (t >= N_NODES * 16) return;
    int n = t >> 4, c16 = t & 15;
    const float* xr = x + (size_t)n * 128 + c16 * 8;
    float d = dis[n];
    float4 lo = *(const float4*)xr;
    float4 hi = *(const float4*)(xr + 4);
    float r[8] = {d * lo.x, d * lo.y, d * lo.z, d * lo.w,
                  d * hi.x, d * hi.y, d * hi.z, d * hi.w};
    Xp[t] = pack8(r);
}

// ---------------- fused aggregate + GEMM (+ optional pool dot) ----------------
// Block = 16 nodes (class-uniform via perm). Group (16 lanes) owns one node's gather.
// u = dis[n]*(sum_nbr T[s] + T[n]) -> A-tile (bf16, LDS) -> M=16 MFMA @ W -> epilogue.
// POOL=0: H[n] = bf16(dis[n]*relu(u@W + b));  POOL=1: ndot[n] = relu(u@W + b) . Wfc
template <int POOL>
__global__ __launch_bounds__(256, 8) void fused_agg_kernel(
    const ushort* __restrict__ T, const uint* __restrict__ csrb,
    const int* __restrict__ rowptr, const int* __restrict__ degi,
    const float* __restrict__ dis, const float* __restrict__ bias,
    const int* __restrict__ perm, const uint4* __restrict__ WB,
    ushort* __restrict__ H, const float* __restrict__ Wfc,
    float* __restrict__ ndot) {
    __shared__ ushort At[16][136];      // 272B row stride (bank-spread)
    __shared__ float disrow[16];
    __shared__ int nid[16];
    __shared__ float pdot[16][4];

    int wave = threadIdx.x >> 6;
    int lane = threadIdx.x & 63;
    int group = lane >> 4;
    int sub = lane & 15;
    uint sub16 = (uint)sub * 16u;
    int r = wave * 4 + group;                       // tile row 0..15
    int node = perm[blockIdx.x * 16 + r];           // grid exact: N_NODES%16==0
    int start = rowptr[node];
    int iters = degi[node] >> 2;
    const char* Tb = (const char*)T;

    float2 acc[4];
#pragma unroll
    for (int i = 0; i < 4; i++) acc[i] = make_float2(0.f, 0.f);

    int jb = start;
    for (int it = 0; it < iters; ++it, jb += 4) {
        // segments are 4-padded and 16B-aligned: one uint4 load = 4 offsets
        uint4 o = *(const uint4*)(csrb + jb);
        uint4 v0 = *(const uint4*)(Tb + (o.x + sub16));
        uint4 v1 = *(const uint4*)(Tb + (o.y + sub16));
        uint4 v2 = *(const uint4*)(Tb + (o.z + sub16));
        uint4 v3 = *(const uint4*)(Tb + (o.w + sub16));
        accp(v0, acc); accp(v1, acc); accp(v2, acc); accp(v3, acc);
    }
    // self term, then scale by dis[node] -> u-row (bf16) into A tile
    {
        uint4 sv = *(const uint4*)(Tb + (((uint)node << 8) + sub16));
        accp(sv, acc);
        float di = dis[node];
        float rr[8] = {di * acc[0].x, di * acc[0].y, di * acc[1].x, di * acc[1].y,
                       di * acc[2].x, di * acc[2].y, di * acc[3].x, di * acc[3].y};
        *(uint4*)&At[r][sub * 8] = pack8(rr);
        if (sub == 0) { disrow[r] = di; nid[r] = node; }
    }
    __syncthreads();

    // MFMA: wave handles nt = wave*2, wave*2+1 over the 16x128 tile
    Frag16 a[4];
    int arow = lane & 15;
    int achunk = lane >> 4;
#pragma unroll
    for (int kt = 0; kt < 4; ++kt)
        a[kt].u = *(const uint4*)&At[arow][kt * 32 + achunk * 8];

    f32x4 c0 = (f32x4){0.f, 0.f, 0.f, 0.f};
    f32x4 c1 = (f32x4){0.f, 0.f, 0.f, 0.f};
    int nt0 = wave * 2, nt1 = wave * 2 + 1;
#pragma unroll
    for (int kt = 0; kt < 4; ++kt) {
        Frag16 b0, b1;
        b0.u = WB[(kt * 8 + nt0) * 64 + lane];
        b1.u = WB[(kt * 8 + nt1) * 64 + lane];
        c0 = __builtin_amdgcn_mfma_f32_16x16x32_bf16(a[kt].s, b0.s, c0, 0, 0, 0);
        c1 = __builtin_amdgcn_mfma_f32_16x16x32_bf16(a[kt].s, b1.s, c1, 0, 0, 0);
    }

    // C layout: col = lane&15, row = (lane>>4)*4 + reg
    int col0 = nt0 * 16 + sub, col1 = nt1 * 16 + sub;
    float b0s = bias[col0], b1s = bias[col1];
    int rq = (lane >> 4) * 4;

    if (POOL == 0) {
        __syncthreads();   // all A-reads done; reuse At as output stage
#pragma unroll
        for (int reg = 0; reg < 4; ++reg) {
            float sc = disrow[rq + reg];
            At[rq + reg][col0] = f2bf_hw(fmaxf(c0[reg] + b0s, 0.f) * sc);
            At[rq + reg][col1] = f2bf_hw(fmaxf(c1[reg] + b1s, 0.f) * sc);
        }
        __syncthreads();
        int row = threadIdx.x >> 4, c16 = threadIdx.x & 15;
        uint4 v = *(const uint4*)&At[row][c16 * 8];
        *(uint4*)((char*)H + (((size_t)(uint)nid[row]) << 8) + c16 * 16) = v;
    } else {
        float wf0 = Wfc[col0], wf1 = Wfc[col1];
        float p[4];
#pragma unroll
        for (int reg = 0; reg < 4; ++reg)
            p[reg] = fmaxf(c0[reg] + b0s, 0.f) * wf0 + fmaxf(c1[reg] + b1s, 0.f) * wf1;
#pragma unroll
        for (int reg = 0; reg < 4; ++reg) {
            p[reg] += __shfl_xor(p[reg], 1);
            p[reg] += __shfl_xor(p[reg], 2);
            p[reg] += __shfl_xor(p[reg], 4);
            p[reg] += __shfl_xor(p[reg], 8);
        }
        if (sub == 0) {
#pragma unroll
            for (int reg = 0; reg < 4; ++reg) pdot[rq + reg][wave] = p[reg];
        }
        __syncthreads();
        if (threadIdx.x < 16) {
            int row = threadIdx.x;
            ndot[nid[row]] = pdot[row][0] + pdot[row][1] + pdot[row][2] + pdot[row][3];
        }
    }
}

// ---------------- pool+fc: one wave per graph over sorted batch ----------------
__global__ __launch_bounds__(64) void pool_fc_kernel(const float* __restrict__ ndot,
                                                     const int* __restrict__ batch,
                                                     const float* __restrict__ bfc,
                                                     float* __restrict__ out) {
    int g = blockIdx.x;
    int lane = threadIdx.x;
    auto lb = [&](int key) {
        int lo = 0, hi = N_NODES;
        while (lo < hi) {
            int mid = (lo + hi) >> 1;
            if (batch[mid] < key) lo = mid + 1; else hi = mid;
        }
        return lo;
    };
    int a = lb(g), b = lb(g + 1);
    float s = 0.f;
    for (int i = a + lane; i < b; i += 64) s += ndot[i];
#pragma unroll
    for (int off = 32; off > 0; off >>= 1) s += __shfl_down(s, off);
    if (lane == 0) out[g] = s / fmaxf((float)(b - a), 1.0f) + bfc[0];
}

// ---------------- launcher ----------------
extern "C" void kernel_launch(void* const* d_in, const int* in_sizes, int n_in,
                              void* d_out, int out_size, void* d_ws, size_t ws_size,
                              hipStream_t stream) {
    const float* x    = (const float*)d_in[0];
    const int*   eidx = (const int*)d_in[1];
    const int*   batch= (const int*)d_in[2];
    const float* W1   = (const float*)d_in[3];
    const float* b1   = (const float*)d_in[4];
    const float* W2   = (const float*)d_in[5];
    const float* b2   = (const float*)d_in[6];
    const float* Wfc  = (const float*)d_in[7];
    const float* bfc  = (const float*)d_in[8];
    float* out = (float*)d_out;

    const int* src = eidx;
    const int* dst = eidx + N_EDGES;

    size_t off = 0;
    char* base = (char*)d_ws;
    auto alloc = [&](size_t bytes) -> void* {
        void* p = base + off;
        off += (bytes + 255) & ~(size_t)255;
        return p;
    };
    int*    bfill   = (int*)alloc(NBUCK * 4);
    int*    clshist = (int*)alloc(NCLS * 4);
    int*    clsfill = (int*)alloc(NCLS * 4);
    int*    clsbase = (int*)alloc(NCLS * 4);
    ushort* A       = (ushort*)alloc((size_t)(N_NODES + 1) * HID * 2);
    ushort* B       = (ushort*)alloc((size_t)(N_NODES + 1) * HID * 2);
    int*    degi    = (int*)alloc(N_NODES * 4);
    int*    rowptr  = (int*)alloc(N_NODES * 4);
    float*  dis     = (float*)alloc(N_NODES * 4);
    float*  ndot    = (float*)alloc(N_NODES * 4);
    int*    perm    = (int*)alloc(N_NODES * 4);
    uint*   csrb    = (uint*)alloc((size_t)NBUCK * BCAP * 4);
    uint*   bucketed= (uint*)alloc((size_t)NBUCK * BCAP * 4);
    uint4*  WB1     = (uint4*)alloc(2048 * 16);
    uint4*  WB2     = (uint4*)alloc(2048 * 16);

    // setup: zero counters + zero rows + W frag pack
    setup_kernel<<<17, 256, 0, stream>>>(bfill, clshist, clsfill,
                                         (uint4*)(A + (size_t)N_NODES * HID),
                                         (uint4*)(B + (size_t)N_NODES * HID),
                                         W1, W2, WB1, WB2);

    // bucketed CSR build (pad-4 + class histogram)
    bucket_scatter_kernel<<<NBLK_A, 256, 0, stream>>>(src, dst, bfill, bucketed);
    bucket_csr_kernel<<<NBUCK, 256, 0, stream>>>(bucketed, bfill, degi, rowptr, dis,
                                                 csrb, clshist);
    clsbase_kernel<<<1, 64, 0, stream>>>(clshist, clsbase);
    perm_kernel<<<(N_NODES + 255) / 256, 256, 0, stream>>>(degi, clsbase, clsfill, perm);

    // X' = bf16(dis * x)
    xprep_kernel<<<(N_NODES * 16 + 255) / 256, 256, 0, stream>>>(x, dis, (uint4*)A);

    int fgrid = N_NODES / 16;   // 6250 exact

    // layer 1: gather X' -> @W1 -> relu -> *dis -> B (h1')
    fused_agg_kernel<0><<<fgrid, 256, 0, stream>>>(A, csrb, rowptr, degi, dis, b1,
                                                   perm, WB1, B, Wfc, ndot);
    // layer 2: gather h1' -> @W2 -> relu -> dot Wfc -> ndot
    fused_agg_kernel<1><<<fgrid, 256, 0, stream>>>(B, csrb, rowptr, degi, dis, b2,
                                                   perm, WB2, B, Wfc, ndot);

    // pool + fc
    pool_fc_kernel<<<N_GRAPHS, 64, 0, stream>>>(ndot, batch, bfc, out);
}

// Round 15
// 204.276 us; speedup vs baseline: 1.1052x; 1.0358x over previous
//
#include <hip/hip_runtime.h>
#include <hip/hip_bf16.h>

#define N_NODES 100000
#define N_EDGES 1600000
#define HID 128
#define N_GRAPHS 256

#define BSHIFT 9
#define BSIZE 512
#define NBUCK ((N_NODES + BSIZE - 1) / BSIZE)   // 196
#define BCAP 12288
#define EPB 8192
#define NBLK_A ((N_EDGES + EPB - 1) / EPB)      // 196
#define NCLS 16
#define ZOFF ((uint)N_NODES << 8)                // byte offset of the zero row

typedef unsigned int uint;
typedef unsigned short ushort;
typedef short short8 __attribute__((ext_vector_type(8)));
typedef float f32x4 __attribute__((ext_vector_type(4)));

__device__ __forceinline__ ushort f2bf_hw(float f) {
    union { __hip_bfloat16 b; ushort u; } cv;
    cv.b = __float2bfloat16(f);
    return cv.u;
}
__device__ __forceinline__ uint4 pack8(const float* r) {
    uint4 o;
    o.x = (uint)f2bf_hw(r[0]) | ((uint)f2bf_hw(r[1]) << 16);
    o.y = (uint)f2bf_hw(r[2]) | ((uint)f2bf_hw(r[3]) << 16);
    o.z = (uint)f2bf_hw(r[4]) | ((uint)f2bf_hw(r[5]) << 16);
    o.w = (uint)f2bf_hw(r[6]) | ((uint)f2bf_hw(r[7]) << 16);
    return o;
}
// accumulate 8 bf16 (packed uint4) into 4 float2 (paired for v_pk_add_f32)
__device__ __forceinline__ void accp(uint4 v, float2* a) {
    a[0].x += __uint_as_float(v.x << 16);
    a[0].y += __uint_as_float(v.x & 0xFFFF0000u);
    a[1].x += __uint_as_float(v.y << 16);
    a[1].y += __uint_as_float(v.y & 0xFFFF0000u);
    a[2].x += __uint_as_float(v.z << 16);
    a[2].y += __uint_as_float(v.z & 0xFFFF0000u);
    a[3].x += __uint_as_float(v.w << 16);
    a[3].y += __uint_as_float(v.w & 0xFFFF0000u);
}

union Frag16 {
    uint4 u;
    short8 s;
    ushort h[8];
};

// ---------------- setup: zero counters + zero rows, and pack W frags ----------------
__global__ void setup_kernel(int* __restrict__ bfill, int* __restrict__ clshist,
                             int* __restrict__ clsfill,
                             uint4* __restrict__ Azr, uint4* __restrict__ Bzr,
                             const float* __restrict__ W1, const float* __restrict__ W2,
                             uint4* __restrict__ WB1, uint4* __restrict__ WB2) {
    if (blockIdx.x == 0) {
        int t = threadIdx.x;
        if (t < NBUCK) bfill[t] = 0;
        if (t < NCLS) { clshist[t] = 0; clsfill[t] = 0; }
        if (t < 16) Azr[t] = (uint4){0, 0, 0, 0};
        else if (t < 32) Bzr[t - 16] = (uint4){0, 0, 0, 0};
        return;
    }
    int t = (blockIdx.x - 1) * 256 + threadIdx.x;   // 0..4095
    const float* W = (t < 2048) ? W1 : W2;
    uint4* WB = (t < 2048) ? WB1 : WB2;
    int tt = t & 2047;
    int lane = tt & 63;
    int nt = (tt >> 6) & 7;
    int kt = tt >> 9;
    int kbase = kt * 32 + (lane >> 4) * 8;
    int col = nt * 16 + (lane & 15);
    float r[8];
#pragma unroll
    for (int j = 0; j < 8; j++) r[j] = W[(size_t)(kbase + j) * 128 + col];
    WB[tt] = pack8(r);
}

// ---------------- bucketed CSR build (dst chunk staged in LDS: one global dst read) ----------------
__global__ __launch_bounds__(256) void bucket_scatter_kernel(const int* __restrict__ src,
                                                             const int* __restrict__ dst,
                                                             int* __restrict__ bfill,
                                                             uint* __restrict__ bucketed) {
    __shared__ int h[NBUCK];
    __shared__ int rb[NBUCK];
    __shared__ int dch[EPB];           // 32 KB dst stage
    for (int t = threadIdx.x; t < NBUCK; t += 256) h[t] = 0;
    __syncthreads();
    int base = blockIdx.x * EPB;
#pragma unroll 4
    for (int it = 0; it < EPB / 256; ++it) {
        int e = base + it * 256 + threadIdx.x;
        if (e < N_EDGES) {
            int d = dst[e];
            dch[it * 256 + threadIdx.x] = d;
            atomicAdd(&h[d >> BSHIFT], 1);
        }
    }
    __syncthreads();
    for (int t = threadIdx.x; t < NBUCK; t += 256) {
        rb[t] = (h[t] ? atomicAdd(&bfill[t], h[t]) : 0) + t * BCAP;
        h[t] = 0;
    }
    __syncthreads();
#pragma unroll 4
    for (int it = 0; it < EPB / 256; ++it) {
        int e = base + it * 256 + threadIdx.x;
        if (e < N_EDGES) {
            int d = dch[it * 256 + threadIdx.x];
            int b = d >> BSHIFT;
            int pos = rb[b] + atomicAdd(&h[b], 1);
            bucketed[pos] = (uint)src[e] | ((uint)(d & (BSIZE - 1)) << 17);
        }
    }
}

// one block per bucket: stage bucket in LDS, count/scan/scatter.
// Segments padded to multiple of 4 (ZOFF fill); degi holds PADDED count;
// also builds the degree-class histogram.
__global__ __launch_bounds__(256) void bucket_csr_kernel(const uint* __restrict__ bucketed,
                                                         const int* __restrict__ bfill,
                                                         int* __restrict__ degi,
                                                         int* __restrict__ rowptr,
                                                         float* __restrict__ dis,
                                                         uint* __restrict__ csrb,
                                                         int* __restrict__ clshist) {
    int b = blockIdx.x;
    int beg = b * BCAP;
    int ne = bfill[b];
    __shared__ uint eb[BCAP];          // 48 KB bucket stage (read bucketed ONCE)
    __shared__ int cnt[BSIZE];
    __shared__ int fl[BSIZE];
    __shared__ int ex[BSIZE];
    __shared__ int ps[256];
    __shared__ int ch[NCLS];
    int t = threadIdx.x;
    cnt[t] = 0; cnt[t + 256] = 0;
    fl[t] = 0;  fl[t + 256] = 0;
    if (t < NCLS) ch[t] = 0;
    __syncthreads();
    for (int i = t; i < ne; i += 256) {
        uint u = bucketed[beg + i];
        eb[i] = u;
        atomicAdd(&cnt[u >> 17], 1);
    }
    __syncthreads();
    int v0 = cnt[2 * t], v1 = cnt[2 * t + 1];
    int p0 = (v0 + 3) & ~3;
    int p1 = (v1 + 3) & ~3;
    int s = p0 + p1;
    ps[t] = s;
    __syncthreads();
    for (int off = 1; off < 256; off <<= 1) {
        int a = (t >= off) ? ps[t - off] : 0;
        __syncthreads();
        ps[t] += a;
        __syncthreads();
    }
    int e0 = ps[t] - s;
    ex[2 * t] = e0;
    ex[2 * t + 1] = e0 + p0;
    int g = b * BSIZE + 2 * t;
    if (g < N_NODES) {
        degi[g] = p0; rowptr[g] = beg + e0;
        dis[g] = rsqrtf(1.0f + (float)v0);
        atomicAdd(&ch[min(p0 >> 2, NCLS - 1)], 1);
    }
    if (g + 1 < N_NODES) {
        degi[g + 1] = p1; rowptr[g + 1] = beg + e0 + p0;
        dis[g + 1] = rsqrtf(1.0f + (float)v1);
        atomicAdd(&ch[min(p1 >> 2, NCLS - 1)], 1);
    }
    __syncthreads();
    if (t < NCLS && ch[t]) atomicAdd(&clshist[t], ch[t]);
    for (int i = t; i < ne; i += 256) {
        uint u = eb[i];
        int dl = u >> 17;
        int p = ex[dl] + atomicAdd(&fl[dl], 1);
        csrb[beg + p] = (u & 0x1FFFFu) << 8;   // byte offset: src * 256
    }
    __syncthreads();
    for (int p = v0; p < p0; ++p) csrb[beg + ex[2 * t] + p] = ZOFF;
    for (int p = v1; p < p1; ++p) csrb[beg + ex[2 * t + 1] + p] = ZOFF;
}

// ---------------- degree-class permutation (clsbase computed in-block from clshist) ----------------
__global__ __launch_bounds__(256) void perm_kernel(const int* __restrict__ degi,
                                                   const int* __restrict__ clshist,
                                                   int* __restrict__ clsfill,
                                                   int* __restrict__ perm) {
    __shared__ int h[NCLS];
    __shared__ int rb[NCLS];
    int t = threadIdx.x;
    if (t < NCLS) h[t] = 0;
    __syncthreads();
    int n = blockIdx.x * 256 + t;
    int cls = 0, myloc = 0;
    if (n < N_NODES) {
        cls = min(degi[n] >> 2, NCLS - 1);
        myloc = atomicAdd(&h[cls], 1);
    }
    __syncthreads();
    if (t < NCLS) {
        int run = 0;
        for (int c = 0; c < t; ++c) run += clshist[c];   // L2-hot, 16 ints
        rb[t] = h[t] ? (run + atomicAdd(&clsfill[t], h[t])) : 0;
    }
    __syncthreads();
    if (n < N_NODES) perm[rb[cls] + myloc] = n;
}

// ---------------- xprep: X' = bf16(dis[n] * x[n]) ----------------
__global__ __launch_bounds__(256) void xprep_kernel(const float* __restrict__ x,
                                                    const float* __restrict__ dis,
                                                    uint4* __restrict__ Xp) {
    int t = blockIdx.x * 256 + threadIdx.x;      // 1.6M = N_NODES*16
    if (t >= N_NODES * 16) return;
    int n = t >> 4, c16 = t & 15;
    const float* xr = x + (size_t)n * 128 + c16 * 8;
    float d = dis[n];
    float4 lo = *(const float4*)xr;
    float4 hi = *(const float4*)(xr + 4);
    float r[8] = {d * lo.x, d * lo.y, d * lo.z, d * lo.w,
                  d * hi.x, d * hi.y, d * hi.z, d * hi.w};
    Xp[t] = pack8(r);
}

// ---------------- fused aggregate + GEMM (+ optional pool dot) ----------------
// Block = 16 nodes (class-uniform via perm). Group (16 lanes) owns one node's gather.
// u = dis[n]*(sum_nbr T[s] + T[n]) -> A-tile (bf16, LDS) -> M=16 MFMA @ W -> epilogue.
// POOL=0: H[n] = bf16(dis[n]*relu(u@W + b));  POOL=1: ndot[n] = relu(u@W + b) . Wfc
template <int POOL>
__global__ __launch_bounds__(256, 8) void fused_agg_kernel(
    const ushort* __restrict__ T, const uint* __restrict__ csrb,
    const int* __restrict__ rowptr, const int* __restrict__ degi,
    const float* __restrict__ dis, const float* __restrict__ bias,
    const int* __restrict__ perm, const uint4* __restrict__ WB,
    ushort* __restrict__ H, const float* __restrict__ Wfc,
    float* __restrict__ ndot) {
    __shared__ ushort At[16][136];      // 272B row stride (bank-spread)
    __shared__ float disrow[16];
    __shared__ int nid[16];
    __shared__ float pdot[16][4];

    int wave = threadIdx.x >> 6;
    int lane = threadIdx.x & 63;
    int group = lane >> 4;
    int sub = lane & 15;
    uint sub16 = (uint)sub * 16u;
    int r = wave * 4 + group;                       // tile row 0..15
    int node = perm[blockIdx.x * 16 + r];           // grid exact: N_NODES%16==0
    int start = rowptr[node];
    int iters = degi[node] >> 2;
    const char* Tb = (const char*)T;

    float2 acc[4];
#pragma unroll
    for (int i = 0; i < 4; i++) acc[i] = make_float2(0.f, 0.f);

    int jb = start;
    for (int it = 0; it < iters; ++it, jb += 4) {
        // segments are 4-padded and 16B-aligned: one uint4 load = 4 offsets
        uint4 o = *(const uint4*)(csrb + jb);
        uint4 v0 = *(const uint4*)(Tb + (o.x + sub16));
        uint4 v1 = *(const uint4*)(Tb + (o.y + sub16));
        uint4 v2 = *(const uint4*)(Tb + (o.z + sub16));
        uint4 v3 = *(const uint4*)(Tb + (o.w + sub16));
        accp(v0, acc); accp(v1, acc); accp(v2, acc); accp(v3, acc);
    }
    // self term, then scale by dis[node] -> u-row (bf16) into A tile
    {
        uint4 sv = *(const uint4*)(Tb + (((uint)node << 8) + sub16));
        accp(sv, acc);
        float di = dis[node];
        float rr[8] = {di * acc[0].x, di * acc[0].y, di * acc[1].x, di * acc[1].y,
                       di * acc[2].x, di * acc[2].y, di * acc[3].x, di * acc[3].y};
        *(uint4*)&At[r][sub * 8] = pack8(rr);
        if (sub == 0) { disrow[r] = di; nid[r] = node; }
    }
    __syncthreads();

    // MFMA: wave handles nt = wave*2, wave*2+1 over the 16x128 tile
    Frag16 a[4];
    int arow = lane & 15;
    int achunk = lane >> 4;
#pragma unroll
    for (int kt = 0; kt < 4; ++kt)
        a[kt].u = *(const uint4*)&At[arow][kt * 32 + achunk * 8];

    f32x4 c0 = (f32x4){0.f, 0.f, 0.f, 0.f};
    f32x4 c1 = (f32x4){0.f, 0.f, 0.f, 0.f};
    int nt0 = wave * 2, nt1 = wave * 2 + 1;
#pragma unroll
    for (int kt = 0; kt < 4; ++kt) {
        Frag16 b0, b1;
        b0.u = WB[(kt * 8 + nt0) * 64 + lane];
        b1.u = WB[(kt * 8 + nt1) * 64 + lane];
        c0 = __builtin_amdgcn_mfma_f32_16x16x32_bf16(a[kt].s, b0.s, c0, 0, 0, 0);
        c1 = __builtin_amdgcn_mfma_f32_16x16x32_bf16(a[kt].s, b1.s, c1, 0, 0, 0);
    }

    // C layout: col = lane&15, row = (lane>>4)*4 + reg
    int col0 = nt0 * 16 + sub, col1 = nt1 * 16 + sub;
    float b0s = bias[col0], b1s = bias[col1];
    int rq = (lane >> 4) * 4;

    if (POOL == 0) {
        __syncthreads();   // all A-reads done; reuse At as output stage
#pragma unroll
        for (int reg = 0; reg < 4; ++reg) {
            float sc = disrow[rq + reg];
            At[rq + reg][col0] = f2bf_hw(fmaxf(c0[reg] + b0s, 0.f) * sc);
            At[rq + reg][col1] = f2bf_hw(fmaxf(c1[reg] + b1s, 0.f) * sc);
        }
        __syncthreads();
        int row = threadIdx.x >> 4, c16 = threadIdx.x & 15;
        uint4 v = *(const uint4*)&At[row][c16 * 8];
        *(uint4*)((char*)H + (((size_t)(uint)nid[row]) << 8) + c16 * 16) = v;
    } else {
        float wf0 = Wfc[col0], wf1 = Wfc[col1];
        float p[4];
#pragma unroll
        for (int reg = 0; reg < 4; ++reg)
            p[reg] = fmaxf(c0[reg] + b0s, 0.f) * wf0 + fmaxf(c1[reg] + b1s, 0.f) * wf1;
#pragma unroll
        for (int reg = 0; reg < 4; ++reg) {
            p[reg] += __shfl_xor(p[reg], 1);
            p[reg] += __shfl_xor(p[reg], 2);
            p[reg] += __shfl_xor(p[reg], 4);
            p[reg] += __shfl_xor(p[reg], 8);
        }
        if (sub == 0) {
#pragma unroll
            for (int reg = 0; reg < 4; ++reg) pdot[rq + reg][wave] = p[reg];
        }
        __syncthreads();
        if (threadIdx.x < 16) {
            int row = threadIdx.x;
            ndot[nid[row]] = pdot[row][0] + pdot[row][1] + pdot[row][2] + pdot[row][3];
        }
    }
}

// ---------------- pool+fc: one wave per graph over sorted batch ----------------
__global__ __launch_bounds__(64) void pool_fc_kernel(const float* __restrict__ ndot,
                                                     const int* __restrict__ batch,
                                                     const float* __restrict__ bfc,
                                                     float* __restrict__ out) {
    int g = blockIdx.x;
    int lane = threadIdx.x;
    auto lb = [&](int key) {
        int lo = 0, hi = N_NODES;
        while (lo < hi) {
            int mid = (lo + hi) >> 1;
            if (batch[mid] < key) lo = mid + 1; else hi = mid;
        }
        return lo;
    };
    int a = lb(g), b = lb(g + 1);
    float s = 0.f;
    for (int i = a + lane; i < b; i += 64) s += ndot[i];
#pragma unroll
    for (int off = 32; off > 0; off >>= 1) s += __shfl_down(s, off);
    if (lane == 0) out[g] = s / fmaxf((float)(b - a), 1.0f) + bfc[0];
}

// ---------------- launcher ----------------
extern "C" void kernel_launch(void* const* d_in, const int* in_sizes, int n_in,
                              void* d_out, int out_size, void* d_ws, size_t ws_size,
                              hipStream_t stream) {
    const float* x    = (const float*)d_in[0];
    const int*   eidx = (const int*)d_in[1];
    const int*   batch= (const int*)d_in[2];
    const float* W1   = (const float*)d_in[3];
    const float* b1   = (const float*)d_in[4];
    const float* W2   = (const float*)d_in[5];
    const float* b2   = (const float*)d_in[6];
    const float* Wfc  = (const float*)d_in[7];
    const float* bfc  = (const float*)d_in[8];
    float* out = (float*)d_out;

    const int* src = eidx;
    const int* dst = eidx + N_EDGES;

    size_t off = 0;
    char* base = (char*)d_ws;
    auto alloc = [&](size_t bytes) -> void* {
        void* p = base + off;
        off += (bytes + 255) & ~(size_t)255;
        return p;
    };
    int*    bfill   = (int*)alloc(NBUCK * 4);
    int*    clshist = (int*)alloc(NCLS * 4);
    int*    clsfill = (int*)alloc(NCLS * 4);
    ushort* A       = (ushort*)alloc((size_t)(N_NODES + 1) * HID * 2);
    ushort* B       = (ushort*)alloc((size_t)(N_NODES + 1) * HID * 2);
    int*    degi    = (int*)alloc(N_NODES * 4);
    int*    rowptr  = (int*)alloc(N_NODES * 4);
    float*  dis     = (float*)alloc(N_NODES * 4);
    float*  ndot    = (float*)alloc(N_NODES * 4);
    int*    perm    = (int*)alloc(N_NODES * 4);
    uint*   csrb    = (uint*)alloc((size_t)NBUCK * BCAP * 4);
    uint*   bucketed= (uint*)alloc((size_t)NBUCK * BCAP * 4);
    uint4*  WB1     = (uint4*)alloc(2048 * 16);
    uint4*  WB2     = (uint4*)alloc(2048 * 16);

    // setup: zero counters + zero rows + W frag pack
    setup_kernel<<<17, 256, 0, stream>>>(bfill, clshist, clsfill,
                                         (uint4*)(A + (size_t)N_NODES * HID),
                                         (uint4*)(B + (size_t)N_NODES * HID),
                                         W1, W2, WB1, WB2);

    // bucketed CSR build (pad-4 + class histogram)
    bucket_scatter_kernel<<<NBLK_A, 256, 0, stream>>>(src, dst, bfill, bucketed);
    bucket_csr_kernel<<<NBUCK, 256, 0, stream>>>(bucketed, bfill, degi, rowptr, dis,
                                                 csrb, clshist);
    perm_kernel<<<(N_NODES + 255) / 256, 256, 0, stream>>>(degi, clshist, clsfill, perm);

    // X' = bf16(dis * x)
    xprep_kernel<<<(N_NODES * 16 + 255) / 256, 256, 0, stream>>>(x, dis, (uint4*)A);

    int fgrid = N_NODES / 16;   // 6250 exact

    // layer 1: gather X' -> @W1 -> relu -> *dis -> B (h1')
    fused_agg_kernel<0><<<fgrid, 256, 0, stream>>>(A, csrb, rowptr, degi, dis, b1,
                                                   perm, WB1, B, Wfc, ndot);
    // layer 2: gather h1' -> @W2 -> relu -> dot Wfc -> ndot
    fused_agg_kernel<1><<<fgrid, 256, 0, stream>>>(B, csrb, rowptr, degi, dis, b2,
                                                   perm, WB2, B, Wfc, ndot);

    // pool + fc
    pool_fc_kernel<<<N_GRAPHS, 64, 0, stream>>>(ndot, batch, bfc, out);
}